// Round 1
// baseline (923.717 us; speedup 1.0000x reference)
//
#include <hip/hip_runtime.h>

// WECT: weighted Euler characteristic transform.
// D=64 directions (lane = direction), H=256 heights, bins = [dir][height].
// LDS histogram layout is [height][dir] so bank = dir%32 -> 2-way (free).

#define HGT 256
#define NDIR 64
#define NBINS (HGT * NDIR)

__global__ void wect_maxnorm(const float* __restrict__ vc, int k0,
                             unsigned* __restrict__ maxbits) {
    float m = 0.f;
    for (int i = blockIdx.x * blockDim.x + threadIdx.x; i < k0;
         i += gridDim.x * blockDim.x) {
        float x = vc[3 * i], y = vc[3 * i + 1], z = vc[3 * i + 2];
        m = fmaxf(m, sqrtf(x * x + y * y + z * z));
    }
    for (int off = 32; off > 0; off >>= 1)
        m = fmaxf(m, __shfl_down(m, off, 64));
    __shared__ float sm[16];
    int wid = threadIdx.x >> 6, lane = threadIdx.x & 63;
    if (lane == 0) sm[wid] = m;
    __syncthreads();
    if (threadIdx.x == 0) {
        float b = sm[0];
        int nw = blockDim.x >> 6;
        for (int w = 1; w < nw; ++w) b = fmaxf(b, sm[w]);
        atomicMax(maxbits, __float_as_uint(b));  // valid: all values >= 0
    }
}

__device__ __forceinline__ int height_bin(float h, float mh, float inv) {
    int idx = (int)ceilf((255.0f * (mh + h)) * inv);
    return min(max(idx, 0), HGT - 1);
}

template <bool STORE>
__global__ __launch_bounds__(1024) void wect_vertex(
    const float* __restrict__ vc, const float* __restrict__ vw,
    const float* __restrict__ dirs, int k0,
    const unsigned* __restrict__ maxbits, unsigned char* __restrict__ vidx,
    float* __restrict__ out) {
    __shared__ float hist[NBINS];
    for (int i = threadIdx.x; i < NBINS; i += blockDim.x) hist[i] = 0.f;
    int lane = threadIdx.x & 63;
    float d0 = dirs[lane * 3], d1 = dirs[lane * 3 + 1], d2 = dirs[lane * 3 + 2];
    float mh = __uint_as_float(*maxbits);
    float inv = 1.0f / (2.0f * mh);
    __syncthreads();
    int wid = (blockIdx.x * blockDim.x + threadIdx.x) >> 6;
    int nw = (gridDim.x * blockDim.x) >> 6;
    for (int k = wid; k < k0; k += nw) {
        float x = vc[3 * k], y = vc[3 * k + 1], z = vc[3 * k + 2];
        float h = x * d0 + y * d1 + z * d2;
        int idx = height_bin(h, mh, inv);
        if (STORE) vidx[(size_t)k * NDIR + lane] = (unsigned char)idx;
        atomicAdd(&hist[idx * NDIR + lane], vw[k]);
    }
    __syncthreads();
    for (int i = threadIdx.x; i < NBINS; i += blockDim.x) {
        float v = hist[i];
        if (v != 0.f) atomicAdd(&out[(i & 63) * HGT + (i >> 6)], v);
    }
}

__global__ __launch_bounds__(512) void wect_simplex_idx(
    const int* __restrict__ edges, const float* __restrict__ ew,
    const int* __restrict__ tris, const float* __restrict__ tw, int k1, int k2,
    const unsigned char* __restrict__ vidx, float* __restrict__ out) {
    __shared__ float hist[NBINS];
    for (int i = threadIdx.x; i < NBINS; i += blockDim.x) hist[i] = 0.f;
    __syncthreads();
    int lane = threadIdx.x & 63;
    int wid = (blockIdx.x * blockDim.x + threadIdx.x) >> 6;
    int nw = (gridDim.x * blockDim.x) >> 6;
    int total = k1 + k2;
    for (int s = wid; s < total; s += nw) {
        int idx;
        float w;
        if (s < k1) {
            int v0 = edges[2 * s], v1 = edges[2 * s + 1];
            int a = vidx[(size_t)v0 * NDIR + lane];
            int b = vidx[(size_t)v1 * NDIR + lane];
            idx = max(a, b);
            w = ew[s];
        } else {
            int t = s - k1;
            int v0 = tris[3 * t], v1 = tris[3 * t + 1], v2 = tris[3 * t + 2];
            int a = vidx[(size_t)v0 * NDIR + lane];
            int b = vidx[(size_t)v1 * NDIR + lane];
            int c = vidx[(size_t)v2 * NDIR + lane];
            idx = max(a, max(b, c));
            w = -tw[t];
        }
        atomicAdd(&hist[idx * NDIR + lane], w);
    }
    __syncthreads();
    for (int i = threadIdx.x; i < NBINS; i += blockDim.x) {
        float v = hist[i];
        if (v != 0.f) atomicAdd(&out[(i & 63) * HGT + (i >> 6)], v);
    }
}

// Fallback when ws is too small for the uint8 vidx table: recompute dots.
__global__ __launch_bounds__(512) void wect_simplex_rec(
    const int* __restrict__ edges, const float* __restrict__ ew,
    const int* __restrict__ tris, const float* __restrict__ tw, int k1, int k2,
    const float* __restrict__ vc, const float* __restrict__ dirs,
    const unsigned* __restrict__ maxbits, float* __restrict__ out) {
    __shared__ float hist[NBINS];
    for (int i = threadIdx.x; i < NBINS; i += blockDim.x) hist[i] = 0.f;
    int lane = threadIdx.x & 63;
    float d0 = dirs[lane * 3], d1 = dirs[lane * 3 + 1], d2 = dirs[lane * 3 + 2];
    float mh = __uint_as_float(*maxbits);
    float inv = 1.0f / (2.0f * mh);
    __syncthreads();
    int wid = (blockIdx.x * blockDim.x + threadIdx.x) >> 6;
    int nw = (gridDim.x * blockDim.x) >> 6;
    int total = k1 + k2;
    for (int s = wid; s < total; s += nw) {
        int idx;
        float w;
        if (s < k1) {
            int v0 = edges[2 * s], v1 = edges[2 * s + 1];
            float h0 = vc[3 * v0] * d0 + vc[3 * v0 + 1] * d1 + vc[3 * v0 + 2] * d2;
            float h1 = vc[3 * v1] * d0 + vc[3 * v1 + 1] * d1 + vc[3 * v1 + 2] * d2;
            idx = max(height_bin(h0, mh, inv), height_bin(h1, mh, inv));
            w = ew[s];
        } else {
            int t = s - k1;
            int v0 = tris[3 * t], v1 = tris[3 * t + 1], v2 = tris[3 * t + 2];
            float h0 = vc[3 * v0] * d0 + vc[3 * v0 + 1] * d1 + vc[3 * v0 + 2] * d2;
            float h1 = vc[3 * v1] * d0 + vc[3 * v1 + 1] * d1 + vc[3 * v1 + 2] * d2;
            float h2 = vc[3 * v2] * d0 + vc[3 * v2 + 1] * d1 + vc[3 * v2 + 2] * d2;
            idx = max(height_bin(h0, mh, inv),
                      max(height_bin(h1, mh, inv), height_bin(h2, mh, inv)));
            w = -tw[t];
        }
        atomicAdd(&hist[idx * NDIR + lane], w);
    }
    __syncthreads();
    for (int i = threadIdx.x; i < NBINS; i += blockDim.x) {
        float v = hist[i];
        if (v != 0.f) atomicAdd(&out[(i & 63) * HGT + (i >> 6)], v);
    }
}

__global__ void wect_cumsum(float* __restrict__ out) {
    // one wave (64 lanes) per direction row of 256 floats
    int lane = threadIdx.x;
    float4* row = (float4*)out + (size_t)blockIdx.x * 64;
    float4 v = row[lane];
    v.y += v.x;
    v.z += v.y;
    v.w += v.z;
    float s = v.w;
    float mine = s;
    for (int off = 1; off < 64; off <<= 1) {
        float t = __shfl_up(s, off, 64);
        if (lane >= off) s += t;
    }
    float excl = s - mine;
    v.x += excl;
    v.y += excl;
    v.z += excl;
    v.w += excl;
    row[lane] = v;
}

extern "C" void kernel_launch(void* const* d_in, const int* in_sizes, int n_in,
                              void* d_out, int out_size, void* d_ws,
                              size_t ws_size, hipStream_t stream) {
    const float* v_coords = (const float*)d_in[0];
    const float* v_weights = (const float*)d_in[1];
    const int* edges = (const int*)d_in[2];
    const float* e_weights = (const float*)d_in[3];
    const int* tris = (const int*)d_in[4];
    const float* t_weights = (const float*)d_in[5];
    const float* dirs = (const float*)d_in[6];
    // d_in[7] = num_heights (=256, hardcoded as HGT)

    int k0 = in_sizes[0] / 3;
    int k1 = in_sizes[2] / 2;
    int k2 = in_sizes[4] / 3;

    float* out = (float*)d_out;
    unsigned* maxbits = (unsigned*)d_ws;
    unsigned char* vidx = (unsigned char*)d_ws + 64;
    bool have_table = ws_size >= (size_t)k0 * NDIR + 64;

    hipMemsetAsync(d_ws, 0, 64, stream);
    hipMemsetAsync(d_out, 0, (size_t)NBINS * sizeof(float), stream);

    wect_maxnorm<<<256, 256, 0, stream>>>(v_coords, k0, maxbits);

    if (have_table) {
        wect_vertex<true><<<256, 1024, 0, stream>>>(v_coords, v_weights, dirs,
                                                    k0, maxbits, vidx, out);
        wect_simplex_idx<<<512, 512, 0, stream>>>(edges, e_weights, tris,
                                                  t_weights, k1, k2, vidx, out);
    } else {
        wect_vertex<false><<<256, 1024, 0, stream>>>(v_coords, v_weights, dirs,
                                                     k0, maxbits, vidx, out);
        wect_simplex_rec<<<512, 512, 0, stream>>>(edges, e_weights, tris,
                                                  t_weights, k1, k2, v_coords,
                                                  dirs, maxbits, out);
    }
    wect_cumsum<<<NDIR, 64, 0, stream>>>(out);
}